// Round 1
// baseline (124.314 us; speedup 1.0000x reference)
//
#include <hip/hip_runtime.h>
#include <hip/hip_bf16.h>

#define CIN  16
#define COUT 16
#define NB   8      // spline bases
#define NF   9      // features per value: silu + 8 bases
#define K2   9      // kernel positions
#define HW   128
#define WC_ELEMS (CIN * K2 * NF * COUT)   // 20736

// grid knots: g[t] = 0.4*t - 2.2, t = 0..11  (grid_range [-1,1], GRID_SIZE=5, order 3)
__device__ __forceinline__ float gknot(int t) { return 0.4f * (float)t - 2.2f; }

// 9 features of one scalar: f[0]=silu(x), f[1..8]=cubic B-spline bases
__device__ __forceinline__ void kan_feat(float x, float* __restrict__ f) {
  f[0] = __fdividef(x, 1.0f + __expf(-x));
  float b[11];
#pragma unroll
  for (int t = 0; t < 11; ++t)
    b[t] = (x >= gknot(t) && x < gknot(t + 1)) ? 1.0f : 0.0f;
#pragma unroll
  for (int k = 1; k <= 3; ++k) {
#pragma unroll
    for (int t = 0; t + k < 11; ++t) {
      float il = 1.0f / (gknot(t + k) - gknot(t));       // constant-folded
      float ir = 1.0f / (gknot(t + k + 1) - gknot(t + 1));
      b[t] = (x - gknot(t)) * il * b[t] + (gknot(t + k + 1) - x) * ir * b[t + 1];
    }
  }
#pragma unroll
  for (int s = 0; s < 8; ++s) f[1 + s] = b[s];
}

// Combine weights: Wc[j][n][c][i]
//   c==0   : sum_m base_weight[i,j,m,n]
//   c==1+s : sum_m spline_weight[i,j,m,n,s] * spline_scaler[i,j,m,n]
__global__ void kan_prep(const float* __restrict__ bw, const float* __restrict__ sw,
                         const float* __restrict__ sc, float* __restrict__ Wc) {
  int idx = blockIdx.x * 256 + threadIdx.x;
  if (idx >= WC_ELEMS) return;
  int i = idx & 15;
  int c = (idx >> 4) % NF;
  int n = (idx / (16 * NF)) % K2;
  int j = idx / (16 * NF * K2);
  float s = 0.f;
  if (c == 0) {
#pragma unroll
    for (int m = 0; m < K2; ++m) s += bw[((i * CIN + j) * K2 + m) * K2 + n];
  } else {
    int si = c - 1;
#pragma unroll
    for (int m = 0; m < K2; ++m) {
      int base = ((i * CIN + j) * K2 + m) * K2 + n;
      s += sw[base * NB + si] * sc[base];
    }
  }
  Wc[idx] = s;
}

__device__ __forceinline__ float load_x(const float* __restrict__ X, int b, int j,
                                        int h0, int w0, int t) {
  int r = t / 18, c = t - r * 18;
  int gh = h0 + r - 1, gw = w0 + c - 1;
  if (gh < 0 || gh >= HW || gw < 0 || gw >= HW) return 0.f;  // padded -> x = 0 (features of 0 still computed!)
  return X[(b * CIN + j) * (HW * HW) + gh * HW + gw];
}

__global__ __launch_bounds__(256) void kan_main(const float* __restrict__ X,
                                                const float* __restrict__ Wc,
                                                const float* __restrict__ bias,
                                                float* __restrict__ out) {
  // features of the 18x18 halo tile, c-dim padded to 12 words for aligned b128 reads
  __shared__ float feat[18 * 18 * 12];

  int bid = blockIdx.x;
  int b = bid >> 6;
  int tile = bid & 63;
  int h0 = (tile >> 3) << 4;
  int w0 = (tile & 7) << 4;
  int tid = threadIdx.x;
  int ty = tid >> 4, tx = tid & 15;

  float acc[16];
#pragma unroll
  for (int i = 0; i < 16; ++i) acc[i] = 0.f;

  // prologue: load x for j=0 (324 values over 256 threads)
  float xv0 = load_x(X, b, 0, h0, w0, tid);
  float xv1 = (tid + 256 < 324) ? load_x(X, b, 0, h0, w0, tid + 256) : 0.f;

#pragma unroll 1
  for (int j = 0; j < CIN; ++j) {
    __syncthreads();  // previous FMA phase done reading LDS
    {
      float f[9];
      kan_feat(xv0, f);
      float* d = &feat[tid * 12];
#pragma unroll
      for (int c = 0; c < 9; ++c) d[c] = f[c];
      if (tid + 256 < 324) {
        kan_feat(xv1, f);
        float* d2 = &feat[(tid + 256) * 12];
#pragma unroll
        for (int c = 0; c < 9; ++c) d2[c] = f[c];
      }
    }
    __syncthreads();  // features ready

    // prefetch next channel's x; latency hides under FMA phase
    float nx0 = 0.f, nx1 = 0.f;
    if (j + 1 < CIN) {
      nx0 = load_x(X, b, j + 1, h0, w0, tid);
      if (tid + 256 < 324) nx1 = load_x(X, b, j + 1, h0, w0, tid + 256);
    }

    const float* wj = Wc + j * (K2 * NF * COUT);  // block-uniform -> s_load
#pragma unroll
    for (int n = 0; n < 9; ++n) {
      int dh = n / 3, dw = n - dh * 3;
      const float* fp = &feat[((ty + dh) * 18 + (tx + dw)) * 12];
      float f[9];
#pragma unroll
      for (int c = 0; c < 9; ++c) f[c] = fp[c];
      const float* wn = wj + n * (NF * COUT);
#pragma unroll
      for (int c = 0; c < 9; ++c) {
#pragma unroll
        for (int i = 0; i < 16; ++i)
          acc[i] = fmaf(f[c], wn[c * 16 + i], acc[i]);
      }
    }
    xv0 = nx0;
    xv1 = nx1;
  }

  int h = h0 + ty, w = w0 + tx;
#pragma unroll
  for (int i = 0; i < 16; ++i)
    out[(b * COUT + i) * (HW * HW) + h * HW + w] = acc[i] + bias[i];
}

extern "C" void kernel_launch(void* const* d_in, const int* in_sizes, int n_in,
                              void* d_out, int out_size, void* d_ws, size_t ws_size,
                              hipStream_t stream) {
  const float* x    = (const float*)d_in[0];
  const float* bw   = (const float*)d_in[1];
  const float* sw   = (const float*)d_in[2];
  const float* sc   = (const float*)d_in[3];
  const float* bias = (const float*)d_in[4];
  float* out = (float*)d_out;
  float* Wc  = (float*)d_ws;   // 20736 floats = 83 KB scratch

  hipLaunchKernelGGL(kan_prep, dim3((WC_ELEMS + 255) / 256), dim3(256), 0, stream,
                     bw, sw, sc, Wc);
  hipLaunchKernelGGL(kan_main, dim3(4 * 64), dim3(256), 0, stream, x, Wc, bias, out);
}

// Round 2
// 68.770 us; speedup vs baseline: 1.8077x; 1.8077x over previous
//
#include <hip/hip_runtime.h>
#include <hip/hip_bf16.h>

#define CIN  16
#define COUT 16
#define NB   8      // spline bases
#define NF   9      // features per value: silu + 8 bases
#define K2   9      // kernel positions
#define HW   128
#define WC_ELEMS (CIN * K2 * NF * COUT)   // 20736
#define PART_FLOATS (4 * COUT * HW * HW)  // one jg partial: 1,048,576 floats = 4 MB

// grid knots: g[t] = 0.4*t - 2.2, t = 0..11  (grid_range [-1,1], GRID_SIZE=5, order 3)
__device__ __forceinline__ float gknot(int t) { return 0.4f * (float)t - 2.2f; }

// 9 features of one scalar: f[0]=silu(x), f[1..8]=cubic B-spline bases
__device__ __forceinline__ void kan_feat(float x, float* __restrict__ f) {
  f[0] = __fdividef(x, 1.0f + __expf(-x));
  float b[11];
#pragma unroll
  for (int t = 0; t < 11; ++t)
    b[t] = (x >= gknot(t) && x < gknot(t + 1)) ? 1.0f : 0.0f;
#pragma unroll
  for (int k = 1; k <= 3; ++k) {
#pragma unroll
    for (int t = 0; t + k < 11; ++t) {
      float il = 1.0f / (gknot(t + k) - gknot(t));       // constant-folded
      float ir = 1.0f / (gknot(t + k + 1) - gknot(t + 1));
      b[t] = (x - gknot(t)) * il * b[t] + (gknot(t + k + 1) - x) * ir * b[t + 1];
    }
  }
#pragma unroll
  for (int s = 0; s < 8; ++s) f[1 + s] = b[s];
}

// Combine weights: Wc[j][n][c][i]
__global__ void kan_prep(const float* __restrict__ bw, const float* __restrict__ sw,
                         const float* __restrict__ sc, float* __restrict__ Wc) {
  int idx = blockIdx.x * 256 + threadIdx.x;
  if (idx >= WC_ELEMS) return;
  int i = idx & 15;
  int c = (idx >> 4) % NF;
  int n = (idx / (16 * NF)) % K2;
  int j = idx / (16 * NF * K2);
  float s = 0.f;
  if (c == 0) {
#pragma unroll
    for (int m = 0; m < K2; ++m) s += bw[((i * CIN + j) * K2 + m) * K2 + n];
  } else {
    int si = c - 1;
#pragma unroll
    for (int m = 0; m < K2; ++m) {
      int base = ((i * CIN + j) * K2 + m) * K2 + n;
      s += sw[base * NB + si] * sc[base];
    }
  }
  Wc[idx] = s;
}

__device__ __forceinline__ float load_x(const float* __restrict__ X, int b, int j,
                                        int h0, int w0, int t) {
  int r = t / 18, c = t - r * 18;
  int gh = h0 + r - 1, gw = w0 + c - 1;
  if (gh < 0 || gh >= HW || gw < 0 || gw >= HW) return 0.f;  // pad: x=0 but features(0) still evaluated
  return X[(b * CIN + j) * (HW * HW) + gh * HW + gw];
}

// Stage 1: each block = (b, 16x16 tile, j-group). Computes sum over its NJ=CIN/JG
// input channels of the KAN contraction; writes fp32 partial (or final if DIRECT).
template <int JG, bool DIRECT>
__global__ __launch_bounds__(256, 4) void kan_stage1(const float* __restrict__ X,
                                                     const float* __restrict__ Wc,
                                                     const float* __restrict__ bias,
                                                     float* __restrict__ dst) {
  __shared__ float feat[18 * 18 * 12];  // stride 12 words/pixel (f[0..8] + pad)

  int bid = blockIdx.x;
  int jg = bid % JG;
  int t2 = bid / JG;
  int b = t2 >> 6;
  int tile = t2 & 63;
  int h0 = (tile >> 3) << 4;
  int w0 = (tile & 7) << 4;
  int tid = threadIdx.x;
  int ty = tid >> 4, tx = tid & 15;

  const int NJ = CIN / JG;
  const int j0 = jg * NJ;

  float acc[16];
#pragma unroll
  for (int i = 0; i < 16; ++i) acc[i] = 0.f;

  float xv0 = load_x(X, b, j0, h0, w0, tid);
  float xv1 = (tid + 256 < 324) ? load_x(X, b, j0, h0, w0, tid + 256) : 0.f;

#pragma unroll 1
  for (int jj = 0; jj < NJ; ++jj) {
    int j = j0 + jj;
    __syncthreads();
    {
      float f[9];
      kan_feat(xv0, f);
      float* d = &feat[tid * 12];
#pragma unroll
      for (int c = 0; c < 9; ++c) d[c] = f[c];
      if (tid + 256 < 324) {
        kan_feat(xv1, f);
        float* d2 = &feat[(tid + 256) * 12];
#pragma unroll
        for (int c = 0; c < 9; ++c) d2[c] = f[c];
      }
    }
    __syncthreads();

    float nx0 = 0.f, nx1 = 0.f;
    if (jj + 1 < NJ) {
      nx0 = load_x(X, b, j + 1, h0, w0, tid);
      if (tid + 256 < 324) nx1 = load_x(X, b, j + 1, h0, w0, tid + 256);
    }

    const float* wj = Wc + j * (K2 * NF * COUT);  // block-uniform -> scalar loads
#pragma unroll
    for (int n = 0; n < 9; ++n) {
      int dh = n / 3, dw = n - dh * 3;
      const float* fp = &feat[((ty + dh) * 18 + (tx + dw)) * 12];
      float f[9];
#pragma unroll
      for (int c = 0; c < 9; ++c) f[c] = fp[c];
      const float* wn = wj + n * (NF * COUT);
#pragma unroll
      for (int c = 0; c < 9; ++c) {
#pragma unroll
        for (int i = 0; i < 16; ++i)
          acc[i] = fmaf(f[c], wn[c * 16 + i], acc[i]);
      }
    }
    xv0 = nx0;
    xv1 = nx1;
  }

  int h = h0 + ty, w = w0 + tx;
  if (DIRECT) {
#pragma unroll
    for (int i = 0; i < 16; ++i)
      dst[(b * COUT + i) * (HW * HW) + h * HW + w] = acc[i] + bias[i];
  } else {
#pragma unroll
    for (int i = 0; i < 16; ++i)
      dst[jg * PART_FLOATS + (b * COUT + i) * (HW * HW) + h * HW + w] = acc[i];
  }
}

// Stage 2: out = sum_jg partial[jg] + bias, vectorized float4
template <int JG>
__global__ __launch_bounds__(256) void kan_stage2(const float* __restrict__ part,
                                                  const float* __restrict__ bias,
                                                  float* __restrict__ out) {
  int idx = blockIdx.x * 256 + threadIdx.x;  // float4 index, 0..262143
  const float4* p = (const float4*)part;
  float4 s = p[idx];
#pragma unroll
  for (int g = 1; g < JG; ++g) {
    float4 q = p[g * (PART_FLOATS / 4) + idx];
    s.x += q.x; s.y += q.y; s.z += q.z; s.w += q.w;
  }
  int i = (idx >> 12) & 15;  // (idx*4 / 16384) % 16
  float bv = bias[i];
  s.x += bv; s.y += bv; s.z += bv; s.w += bv;
  ((float4*)out)[idx] = s;
}

extern "C" void kernel_launch(void* const* d_in, const int* in_sizes, int n_in,
                              void* d_out, int out_size, void* d_ws, size_t ws_size,
                              hipStream_t stream) {
  const float* x    = (const float*)d_in[0];
  const float* bw   = (const float*)d_in[1];
  const float* sw   = (const float*)d_in[2];
  const float* sc   = (const float*)d_in[3];
  const float* bias = (const float*)d_in[4];
  float* out = (float*)d_out;

  const size_t part_bytes = (size_t)PART_FLOATS * 4;
  const size_t wc_bytes = (size_t)WC_ELEMS * 4;

  int JG;
  if (ws_size >= 4 * part_bytes + wc_bytes) JG = 4;
  else if (ws_size >= 2 * part_bytes + wc_bytes) JG = 2;
  else JG = 1;

  float* part = (float*)d_ws;
  float* Wc = (JG > 1) ? (float*)((char*)d_ws + (size_t)JG * part_bytes)
                       : (float*)d_ws;

  hipLaunchKernelGGL(kan_prep, dim3((WC_ELEMS + 255) / 256), dim3(256), 0, stream,
                     bw, sw, sc, Wc);

  if (JG == 4) {
    hipLaunchKernelGGL((kan_stage1<4, false>), dim3(4 * 64 * 4), dim3(256), 0, stream,
                       x, Wc, bias, part);
    hipLaunchKernelGGL((kan_stage2<4>), dim3((PART_FLOATS / 4) / 256), dim3(256), 0, stream,
                       part, bias, out);
  } else if (JG == 2) {
    hipLaunchKernelGGL((kan_stage1<2, false>), dim3(4 * 64 * 2), dim3(256), 0, stream,
                       x, Wc, bias, part);
    hipLaunchKernelGGL((kan_stage2<2>), dim3((PART_FLOATS / 4) / 256), dim3(256), 0, stream,
                       part, bias, out);
  } else {
    hipLaunchKernelGGL((kan_stage1<1, true>), dim3(4 * 64), dim3(256), 0, stream,
                       x, Wc, bias, out);
  }
}

// Round 3
// 33.558 us; speedup vs baseline: 3.7044x; 2.0493x over previous
//
#include <hip/hip_runtime.h>
#include <hip/hip_bf16.h>

#define HW   128
#define CIN  16
#define COUT 16

typedef __attribute__((ext_vector_type(8))) short bf16x8;
typedef __attribute__((ext_vector_type(4))) float f32x4;

__device__ __forceinline__ float gknot(int t) { return 0.4f * (float)t - 2.2f; }

__device__ __forceinline__ ushort f2bf(float x) {
  uint u = __builtin_bit_cast(uint, x);
  u += 0x7FFFu + ((u >> 16) & 1u);   // RNE; inputs are finite
  return (ushort)(u >> 16);
}

__device__ __forceinline__ uint bpack(float a, float b) {
  return (uint)f2bf(a) | ((uint)f2bf(b) << 16);
}

// f[0]=silu(x), f[1..8]=cubic B-spline bases, f[9..11]=0 (c-pad)
__device__ __forceinline__ void kan_feat12(float x, float* __restrict__ f) {
  f[0] = __fdividef(x, 1.0f + __expf(-x));
  float b[11];
#pragma unroll
  for (int t = 0; t < 11; ++t)
    b[t] = (x >= gknot(t) && x < gknot(t + 1)) ? 1.0f : 0.0f;
#pragma unroll
  for (int k = 1; k <= 3; ++k) {
#pragma unroll
    for (int t = 0; t + k < 11; ++t) {
      float il = 1.0f / (gknot(t + k) - gknot(t));       // constant-folded
      float ir = 1.0f / (gknot(t + k + 1) - gknot(t + 1));
      b[t] = (x - gknot(t)) * il * b[t] + (gknot(t + k + 1) - x) * ir * b[t + 1];
    }
  }
#pragma unroll
  for (int s = 0; s < 8; ++s) f[1 + s] = b[s];
  f[9] = 0.f; f[10] = 0.f; f[11] = 0.f;
}

// Wb flat index: ((((jg*9 + n)*3 + cc)*16 + i)*4 + q)*8 + jl   (bf16)
// value = combined weight W(i, j = jg*8+jl, n, c = cc*4+q); c==0 base, 1..8 spline, >=9 zero
__global__ void kan_prep(const float* __restrict__ bw, const float* __restrict__ sw,
                         const float* __restrict__ sc, ushort* __restrict__ Wb) {
  int idx = blockIdx.x * 256 + threadIdx.x;
  if (idx >= 27648) return;
  int jl = idx & 7;
  int q  = (idx >> 3) & 3;
  int i  = (idx >> 5) & 15;
  int rest = idx >> 9;
  int cc = rest % 3;
  int tt = rest / 3;
  int n  = tt % 9;
  int jg = tt / 9;
  int c = cc * 4 + q;
  int j = jg * 8 + jl;
  float s = 0.f;
  if (c == 0) {
#pragma unroll
    for (int m = 0; m < 9; ++m) s += bw[((i * 16 + j) * 9 + m) * 9 + n];
  } else if (c <= 8) {
#pragma unroll
    for (int m = 0; m < 9; ++m) {
      int base = ((i * 16 + j) * 9 + m) * 9 + n;
      s += sw[base * 8 + (c - 1)] * sc[base];
    }
  }
  Wb[idx] = f2bf(s);
}

#define PSTRIDE 208            // bytes per halo pixel in LDS: c12*j8*2 + 16 pad (bank-balanced)
#define LDS_BYTES (180 * PSTRIDE)

__device__ __forceinline__ void mfma_pass(f32x4& acc, const char* __restrict__ smem,
                                          int lane_base, const bf16x8* __restrict__ Bf) {
#pragma unroll
  for (int n = 0; n < 9; ++n) {
    const int dh = n / 3, dw = n % 3;
#pragma unroll
    for (int cc = 0; cc < 3; ++cc) {
      bf16x8 av = *reinterpret_cast<const bf16x8*>(
          smem + lane_base + ((dh * 18 + dw) * PSTRIDE + cc * 64));
      acc = __builtin_amdgcn_mfma_f32_16x16x32_bf16(av, Bf[n * 3 + cc], acc, 0, 0, 0);
    }
  }
}

__global__ __launch_bounds__(512, 2) void kan_mfma(
    const float* __restrict__ X, const ushort* __restrict__ Wb,
    const float* __restrict__ bias, float* __restrict__ out) {
  __shared__ char smem[LDS_BYTES];   // feat[p=hh*18+ww][c12][j8] bf16, stride 208B

  int tid = threadIdx.x;
  int lane = tid & 63;
  int wl = tid >> 6;              // wave id = output row within the 8-row half
  int bid = blockIdx.x;
  int b = bid >> 6;
  int tile = bid & 63;
  int h0 = (tile >> 3) << 4;
  int w0 = (tile & 7) << 4;

  int li = lane & 15;             // B/D: out-channel i ; A: w-column
  int lq = lane >> 4;             // k-chunk quarter

  float bias_v = bias[li];

  int lane_base = (wl * 18 + li) * PSTRIDE + lq * 16;   // A-frag base (row wl, col li)
  int woff = li * 64 + lq * 16;                          // B-frag lane offset in 1KB chunk

  f32x4 acc0 = {0.f, 0.f, 0.f, 0.f};
  f32x4 acc1 = {0.f, 0.f, 0.f, 0.f};
  bf16x8 Bf[27];

#pragma unroll 1
  for (int jg = 0; jg < 2; ++jg) {
#pragma unroll 1
    for (int half = 0; half < 2; ++half) {
      __syncthreads();            // previous MFMA phase done reading LDS
      // ---- feature phase: 180 halo pixels x 2 j-quads = 360 tasks ----
      if (tid < 360) {
        int p = tid >> 1, jq = tid & 1;
        int hh = p / 18, ww = p - hh * 18;
        int gh = h0 + half * 8 + hh - 1;
        int gw = w0 + ww - 1;
        bool inb = (gh >= 0) & (gh < HW) & (gw >= 0) & (gw < HW);
        const float* xp = X + ((b * 16 + jg * 8 + jq * 4) << 14) + (gh << 7) + gw;
        float f[4][12];
#pragma unroll
        for (int jj = 0; jj < 4; ++jj) {
          float xv = inb ? xp[jj << 14] : 0.f;   // pad: x=0, features still evaluated
          kan_feat12(xv, f[jj]);
        }
        char* wp = smem + p * PSTRIDE + jq * 8;
#pragma unroll
        for (int c = 0; c < 12; ++c) {
          uint2 v;
          v.x = bpack(f[0][c], f[1][c]);
          v.y = bpack(f[2][c], f[3][c]);
          *reinterpret_cast<uint2*>(wp + c * 16) = v;
        }
      }
      if (half == 0) {
        // hoist B-frags for this j-group (L2-resident); overlaps the barrier
        const char* wbase = (const char*)Wb + jg * (27 * 1024) + woff;
#pragma unroll
        for (int t = 0; t < 27; ++t)
          Bf[t] = *reinterpret_cast<const bf16x8*>(wbase + t * 1024);
      }
      __syncthreads();            // features visible
      // ---- MFMA phase: 9 taps x 3 c-chunks ----
      if (half == 0) mfma_pass(acc0, smem, lane_base, Bf);
      else           mfma_pass(acc1, smem, lane_base, Bf);
    }
  }

  // ---- epilogue: D lane holds i = li, pixels w = lq*4 + [0..3] ----
#pragma unroll
  for (int half = 0; half < 2; ++half) {
    f32x4 a = half ? acc1 : acc0;
    int h = h0 + half * 8 + wl;
    float* op = out + ((b * 16 + li) << 14) + (h << 7) + w0 + lq * 4;
    float4 v;
    v.x = a[0] + bias_v; v.y = a[1] + bias_v;
    v.z = a[2] + bias_v; v.w = a[3] + bias_v;
    *reinterpret_cast<float4*>(op) = v;
  }
}

extern "C" void kernel_launch(void* const* d_in, const int* in_sizes, int n_in,
                              void* d_out, int out_size, void* d_ws, size_t ws_size,
                              hipStream_t stream) {
  const float* x    = (const float*)d_in[0];
  const float* bw   = (const float*)d_in[1];
  const float* sw   = (const float*)d_in[2];
  const float* sc   = (const float*)d_in[3];
  const float* bias = (const float*)d_in[4];
  float* out = (float*)d_out;
  ushort* Wb = (ushort*)d_ws;   // 27648 bf16 = 55296 B

  hipLaunchKernelGGL(kan_prep, dim3(108), dim3(256), 0, stream, bw, sw, sc, Wb);
  hipLaunchKernelGGL(kan_mfma, dim3(256), dim3(512), 0, stream, x, Wb, bias, out);
}

// Round 4
// 29.565 us; speedup vs baseline: 4.2048x; 1.1351x over previous
//
#include <hip/hip_runtime.h>
#include <hip/hip_bf16.h>

#define HW 128

typedef __attribute__((ext_vector_type(8))) short bf16x8;
typedef __attribute__((ext_vector_type(4))) float f32x4;

__device__ __forceinline__ float gknot(int t) { return 0.4f * (float)t - 2.2f; }

__device__ __forceinline__ ushort f2bf(float x) {
  uint u = __builtin_bit_cast(uint, x);
  u += 0x7FFFu + ((u >> 16) & 1u);   // RNE; inputs finite
  return (ushort)(u >> 16);
}
__device__ __forceinline__ uint bpack(float a, float b) {
  return (uint)f2bf(a) | ((uint)f2bf(b) << 16);
}

// f[0]=silu(x), f[1..8]=cubic B-spline bases, f[9]=0 (pad)
__device__ __forceinline__ void kan_feat10(float x, float* __restrict__ f) {
  f[0] = __fdividef(x, 1.0f + __expf(-x));
  float b[11];
#pragma unroll
  for (int t = 0; t < 11; ++t)
    b[t] = (x >= gknot(t) && x < gknot(t + 1)) ? 1.0f : 0.0f;
#pragma unroll
  for (int k = 1; k <= 3; ++k) {
#pragma unroll
    for (int t = 0; t + k < 11; ++t) {
      float il = 1.0f / (gknot(t + k) - gknot(t));       // constant-folded
      float ir = 1.0f / (gknot(t + k + 1) - gknot(t + 1));
      b[t] = (x - gknot(t)) * il * b[t] + (gknot(t + k + 1) - x) * ir * b[t + 1];
    }
  }
#pragma unroll
  for (int s = 0; s < 8; ++s) f[1 + s] = b[s];
  f[9] = 0.f;
}

// B layout: Wb[((t*16 + i)*4 + lq)*8 + e]  (bf16), t = n*5+q (45 chunks of 1KB)
// k = q*32 + lq*8 + e in [0,160): j = k/10, c = k%10
// value: c==0 -> sum_m base_w; c in 1..8 -> sum_m spline_w[c-1]*scaler; c==9 -> 0
__global__ void kan_prep(const float* __restrict__ bw, const float* __restrict__ sw,
                         const float* __restrict__ sc, ushort* __restrict__ Wb) {
  int idx = blockIdx.x * 256 + threadIdx.x;
  if (idx >= 45 * 512) return;
  int e  = idx & 7;
  int lq = (idx >> 3) & 3;
  int i  = (idx >> 5) & 15;
  int t  = idx >> 9;
  int n = t / 5, q = t % 5;
  int k = q * 32 + lq * 8 + e;
  int j = k / 10, c = k % 10;
  float s = 0.f;
  if (c == 0) {
#pragma unroll
    for (int m = 0; m < 9; ++m) s += bw[((i * 16 + j) * 9 + m) * 9 + n];
  } else if (c <= 8) {
#pragma unroll
    for (int m = 0; m < 9; ++m) {
      int base = ((i * 16 + j) * 9 + m) * 9 + n;
      s += sw[base * 8 + (c - 1)] * sc[base];
    }
  }
  Wb[idx] = f2bf(s);
}

#define PSTRIDE 336                 // 160 bf16 (k=j*10+c) + 16B pad; 84 words -> bank-uniform
#define HALO_PX 180                 // 10 rows x 18 cols

// feature task: pixel p (10x18 halo), jq in {0,1} = channels jq*8..jq*8+7
__device__ __forceinline__ void feat_task(const float* __restrict__ X, char* __restrict__ smem,
                                          int b, int h0, int w0, int p, int jq) {
  int hh = p / 18, ww = p - hh * 18;
  int gh = h0 + hh - 1, gw = w0 + ww - 1;
  bool inb = (gh >= 0) & (gh < HW) & (gw >= 0) & (gw < HW);
  const float* xp = X + ((b * 16 + jq * 8) << 14) + (gh << 7) + gw;
  char* wp = smem + p * PSTRIDE + jq * 160;
#pragma unroll
  for (int jl = 0; jl < 8; ++jl) {
    float xv = inb ? xp[jl << 14] : 0.f;   // pad pixels: x=0, features still evaluated
    float f[10];
    kan_feat10(xv, f);
    uint* d = (uint*)(wp + jl * 20);
    d[0] = bpack(f[0], f[1]);
    d[1] = bpack(f[2], f[3]);
    d[2] = bpack(f[4], f[5]);
    d[3] = bpack(f[6], f[7]);
    d[4] = bpack(f[8], 0.f);
  }
}

__global__ __launch_bounds__(256, 2) void kan_mfma(
    const float* __restrict__ X, const ushort* __restrict__ Wb,
    const float* __restrict__ bias, float* __restrict__ out) {
  __shared__ char smem[HALO_PX * PSTRIDE];   // 60480 B

  int tid = threadIdx.x;
  int lane = tid & 63;
  int wid = tid >> 6;                 // 4 waves; wave owns output rows wid and wid+4
  int bid = blockIdx.x;
  int b = bid >> 7;
  int tile = bid & 127;
  int h0 = (tile >> 3) << 3;          // 16 row-tiles of 8
  int w0 = (tile & 7) << 4;           // 8 col-tiles of 16
  int li = lane & 15;
  int lq = lane >> 4;

  const char* wbase = (const char*)Wb + li * 64 + lq * 16;

  // B sub-pass 0 issued before features: L2 latency hides under feature phase
  bf16x8 Bbuf[2][15];
#pragma unroll
  for (int t = 0; t < 15; ++t)
    Bbuf[0][t] = *(const bf16x8*)(wbase + t * 1024);

  // ---- feature phase: 360 tasks over 256 threads ----
  {
    int p = (tid < 180) ? tid : tid - 180;
    int jq = (tid < 180) ? 0 : 1;
    feat_task(X, smem, b, h0, w0, p, jq);
    if (tid < 104) feat_task(X, smem, b, h0, w0, tid + 76, 1);  // tasks 256..359
  }
  __syncthreads();

  // ---- MFMA phase: 3 sub-passes x (5 chunks x 3 taps) x 2 rows ----
  f32x4 acc0 = {0.f, 0.f, 0.f, 0.f};
  f32x4 acc1 = {0.f, 0.f, 0.f, 0.f};
  int ab = li * 336 + lq * 16;
  const char* base0 = smem + wid * (18 * 336) + ab;          // row wid
  const char* base1 = smem + (wid + 4) * (18 * 336) + ab;    // row wid+4

#pragma unroll
  for (int s = 0; s < 3; ++s) {
    if (s < 2) {
#pragma unroll
      for (int t = 0; t < 15; ++t)
        Bbuf[(s + 1) & 1][t] = *(const bf16x8*)(wbase + ((s + 1) * 15 + t) * 1024);
    }
#pragma unroll
    for (int tt = 0; tt < 15; ++tt) {
      const int t = s * 15 + tt;
      const int n = t / 5, q = t - n * 5;
      const int dh = n / 3, dw = n - dh * 3;
      const int imm = (dh * 18 + dw) * 336 + q * 64;
      bf16x8 a0 = *(const bf16x8*)(base0 + imm);
      acc0 = __builtin_amdgcn_mfma_f32_16x16x32_bf16(a0, Bbuf[s & 1][tt], acc0, 0, 0, 0);
      bf16x8 a1 = *(const bf16x8*)(base1 + imm);
      acc1 = __builtin_amdgcn_mfma_f32_16x16x32_bf16(a1, Bbuf[s & 1][tt], acc1, 0, 0, 0);
    }
  }

  // ---- epilogue: lane holds i=li, pixels w = lq*4 + reg, rows wid / wid+4 ----
  float bias_v = bias[li];
  float* op0 = out + ((b * 16 + li) << 14) + ((h0 + wid) << 7) + w0 + lq * 4;
  float* op1 = out + ((b * 16 + li) << 14) + ((h0 + wid + 4) << 7) + w0 + lq * 4;
  float4 v0, v1;
  v0.x = acc0[0] + bias_v; v0.y = acc0[1] + bias_v;
  v0.z = acc0[2] + bias_v; v0.w = acc0[3] + bias_v;
  v1.x = acc1[0] + bias_v; v1.y = acc1[1] + bias_v;
  v1.z = acc1[2] + bias_v; v1.w = acc1[3] + bias_v;
  *reinterpret_cast<float4*>(op0) = v0;
  *reinterpret_cast<float4*>(op1) = v1;
}

extern "C" void kernel_launch(void* const* d_in, const int* in_sizes, int n_in,
                              void* d_out, int out_size, void* d_ws, size_t ws_size,
                              hipStream_t stream) {
  const float* x    = (const float*)d_in[0];
  const float* bw   = (const float*)d_in[1];
  const float* sw   = (const float*)d_in[2];
  const float* sc   = (const float*)d_in[3];
  const float* bias = (const float*)d_in[4];
  float* out = (float*)d_out;
  ushort* Wb = (ushort*)d_ws;   // 45*512 bf16 = 46080 B

  hipLaunchKernelGGL(kan_prep, dim3(90), dim3(256), 0, stream, bw, sw, sc, Wb);
  hipLaunchKernelGGL(kan_mfma, dim3(512), dim3(256), 0, stream, x, Wb, bias, out);
}

// Round 5
// 21.816 us; speedup vs baseline: 5.6983x; 1.3552x over previous
//
#include <hip/hip_runtime.h>
#include <hip/hip_bf16.h>

#define HW 128

typedef __attribute__((ext_vector_type(8))) short bf16x8;
typedef __attribute__((ext_vector_type(4))) float f32x4;

__device__ __forceinline__ ushort f2bf(float x) {
  uint u = __builtin_bit_cast(uint, x);
  u += 0x7FFFu + ((u >> 16) & 1u);   // RNE; inputs finite
  return (ushort)(u >> 16);
}
__device__ __forceinline__ float gknot(int t) { return 0.4f * (float)t - 2.2f; }

// B layout: Wb[((t*16 + i)*4 + lq)*8 + e]  (bf16), t = n*5+q (45 chunks of 1KB)
// k = q*32 + lq*8 + e in [0,160): j = k/10, c = k%10
// value: c==0 -> sum_m base_w; c in 1..8 -> sum_m spline_w[c-1]*scaler; c==9 -> 0
__global__ void kan_prep(const float* __restrict__ bw, const float* __restrict__ sw,
                         const float* __restrict__ sc, ushort* __restrict__ Wb) {
  int idx = blockIdx.x * 256 + threadIdx.x;
  if (idx >= 45 * 512) return;
  int e  = idx & 7;
  int lq = (idx >> 3) & 3;
  int i  = (idx >> 5) & 15;
  int t  = idx >> 9;
  int n = t / 5, q = t % 5;
  int k = q * 32 + lq * 8 + e;
  int j = k / 10, c = k % 10;
  float s = 0.f;
  if (c == 0) {
#pragma unroll
    for (int m = 0; m < 9; ++m) s += bw[((i * 16 + j) * 9 + m) * 9 + n];
  } else if (c <= 8) {
#pragma unroll
    for (int m = 0; m < 9; ++m) {
      int base = ((i * 16 + j) * 9 + m) * 9 + n;
      s += sw[base * 8 + (c - 1)] * sc[base];
    }
  }
  Wb[idx] = f2bf(s);
}

#define PSTRIDE 336                 // 160 bf16 (k=j*10+c) + 16B pad; bank-uniform A-reads
#define HALO_PX 180                 // 10 rows x 18 cols

// Closed-form uniform cubic B-spline features: silu + 4 nonzero bases scattered.
// blk: 20B block for (pixel, channel); dump: pixel pad bytes (never read).
__device__ __forceinline__ void kan_feat_store(char* __restrict__ blk,
                                               char* __restrict__ dump, float x) {
  float sil = __fdividef(x, 1.0f + __expf(-x));
  float t = (x + 2.2f) * 2.5f;
  float fi = floorf(t);
  float u = t - fi;
  int i = (int)fi;
  float u2 = u * u, u3 = u2 * u;
  float v = 1.0f - u;
  float B0 = v * v * v * (1.0f / 6.0f);
  float B1 = fmaf(0.5f, u3, (2.0f / 3.0f) - u2);
  float B2 = fmaf(0.5f, (u + u2) - u3, 1.0f / 6.0f);
  float B3 = u3 * (1.0f / 6.0f);

  uint* w = (uint*)blk;
  w[0] = (uint)f2bf(sil);   // (silu, 0)
  w[1] = 0; w[2] = 0; w[3] = 0; w[4] = 0;

  // nonzero bases at s = i-3+d, d=0..3; valid iff (uint)s < 8 (covers range check)
  char* pa = blk + 2 * i - 4;   // = blk + 2*(1 + (i-3))
#pragma unroll
  for (int d = 0; d < 4; ++d) {
    float B = (d == 0) ? B0 : (d == 1) ? B1 : (d == 2) ? B2 : B3;
    bool ok = (unsigned)(i - 3 + d) < 8u;
    char* addr = ok ? (pa + 2 * d) : dump;
    *(ushort*)addr = f2bf(B);
  }
}

__global__ __launch_bounds__(256, 2) void kan_mfma(
    const float* __restrict__ X, const ushort* __restrict__ Wb,
    const float* __restrict__ bias, float* __restrict__ out) {
  __shared__ char smem[HALO_PX * PSTRIDE];   // 60480 B

  int tid = threadIdx.x;
  int lane = tid & 63;
  int wid = tid >> 6;                 // 4 waves; wave owns output rows wid, wid+4
  int bid = blockIdx.x;
  int b = bid >> 7;
  int tile = bid & 127;
  int h0 = (tile >> 3) << 3;          // 16 row-tiles of 8
  int w0 = (tile & 7) << 4;           // 8 col-tiles of 16
  int li = lane & 15;
  int lq = lane >> 4;

  const char* wbase = (const char*)Wb + li * 64 + lq * 16;

  // B sub-pass 0 issued before features: L2 latency hides under feature phase
  bf16x8 Bbuf[2][15];
#pragma unroll
  for (int t = 0; t < 15; ++t)
    Bbuf[0][t] = *(const bf16x8*)(wbase + t * 1024);

  // ---- feature phase: 720 quad-tasks (180 px x 4 channel-quads) ----
#pragma unroll
  for (int r = 0; r < 3; ++r) {
    int tq = r * 256 + tid;
    if (tq < 720) {
      int p = tq >> 2, jq = tq & 3;
      int hh = p / 18, ww = p - hh * 18;
      int gh = h0 + hh - 1, gw = w0 + ww - 1;
      bool inb = (gh >= 0) & (gh < HW) & (gw >= 0) & (gw < HW);
      const float* xp = X + ((b * 16 + jq * 4) << 14) + (gh << 7) + gw;
      char* pix = smem + p * PSTRIDE;
      char* blk = pix + jq * 80;
      char* dump = pix + 326;
#pragma unroll
      for (int jl = 0; jl < 4; ++jl) {
        float xv = inb ? xp[jl << 14] : 0.f;  // pad pixel: x=0, features still stored
        kan_feat_store(blk + jl * 20, dump, xv);
      }
    }
  }
  __syncthreads();

  // ---- MFMA phase: 3 sub-passes x (5 chunks x 3 taps) x 2 rows ----
  f32x4 acc0 = {0.f, 0.f, 0.f, 0.f};
  f32x4 acc1 = {0.f, 0.f, 0.f, 0.f};
  int ab = li * PSTRIDE + lq * 16;
  const char* base0 = smem + wid * (18 * PSTRIDE) + ab;          // row wid
  const char* base1 = smem + (wid + 4) * (18 * PSTRIDE) + ab;    // row wid+4

#pragma unroll
  for (int s = 0; s < 3; ++s) {
    if (s < 2) {
#pragma unroll
      for (int t = 0; t < 15; ++t)
        Bbuf[(s + 1) & 1][t] = *(const bf16x8*)(wbase + ((s + 1) * 15 + t) * 1024);
    }
#pragma unroll
    for (int tt = 0; tt < 15; ++tt) {
      const int t = s * 15 + tt;
      const int n = t / 5, q = t - n * 5;
      const int dh = n / 3, dw = n - dh * 3;
      const int imm = (dh * 18 + dw) * PSTRIDE + q * 64;
      bf16x8 a0 = *(const bf16x8*)(base0 + imm);
      acc0 = __builtin_amdgcn_mfma_f32_16x16x32_bf16(a0, Bbuf[s & 1][tt], acc0, 0, 0, 0);
      bf16x8 a1 = *(const bf16x8*)(base1 + imm);
      acc1 = __builtin_amdgcn_mfma_f32_16x16x32_bf16(a1, Bbuf[s & 1][tt], acc1, 0, 0, 0);
    }
  }

  // ---- epilogue: lane holds i=li, pixels w = lq*4 + reg, rows wid / wid+4 ----
  float bias_v = bias[li];
  float* op0 = out + ((b * 16 + li) << 14) + ((h0 + wid) << 7) + w0 + lq * 4;
  float* op1 = out + ((b * 16 + li) << 14) + ((h0 + wid + 4) << 7) + w0 + lq * 4;
  float4 v0, v1;
  v0.x = acc0[0] + bias_v; v0.y = acc0[1] + bias_v;
  v0.z = acc0[2] + bias_v; v0.w = acc0[3] + bias_v;
  v1.x = acc1[0] + bias_v; v1.y = acc1[1] + bias_v;
  v1.z = acc1[2] + bias_v; v1.w = acc1[3] + bias_v;
  *reinterpret_cast<float4*>(op0) = v0;
  *reinterpret_cast<float4*>(op1) = v1;
}

extern "C" void kernel_launch(void* const* d_in, const int* in_sizes, int n_in,
                              void* d_out, int out_size, void* d_ws, size_t ws_size,
                              hipStream_t stream) {
  const float* x    = (const float*)d_in[0];
  const float* bw   = (const float*)d_in[1];
  const float* sw   = (const float*)d_in[2];
  const float* sc   = (const float*)d_in[3];
  const float* bias = (const float*)d_in[4];
  float* out = (float*)d_out;
  ushort* Wb = (ushort*)d_ws;   // 45*512 bf16 = 46080 B

  hipLaunchKernelGGL(kan_prep, dim3(90), dim3(256), 0, stream, bw, sw, sc, Wb);
  hipLaunchKernelGGL(kan_mfma, dim3(512), dim3(256), 0, stream, x, Wb, bias, out);
}